// Round 1
// baseline (52922.150 us; speedup 1.0000x reference)
//
#include <hip/hip_runtime.h>
#include <hip/hip_cooperative_groups.h>

namespace cg = cooperative_groups;

// Problem dims
#define EPN  512
#define T1N  1024
#define NIN  128
#define HSN  256
#define OUTN 64
#define G3N  768   // 3*HSN

// Grid layout: one persistent cooperative kernel.
// Per inter-barrier slot s: blocks [0,256) compute h_new(s) (32x32 tiles),
// blocks [256,272) compute P(s-1), blocks [272,304) compute final(s-2).
#define A_BLOCKS 256
#define B_BLOCKS 16
#define C_BLOCKS 32
#define NBLK     304
#define NTHR     256

struct KArgs {
  const float *x, *h0, *W_ih, *W_hh, *b_ih, *b_hh, *W_hr, *b_hr, *W_reg, *b_reg;
  float *out;
  float *WT_ih, *WT_hh, *WregT, *Sreg, *hb0, *hb1, *PT0, *PT1;
};

struct F4 { float x, y, z, w; };
__device__ __forceinline__ void fma4(F4& a, float s, const float4& b) {
  a.x += s * b.x; a.y += s * b.y; a.z += s * b.z; a.w += s * b.w;
}
__device__ __forceinline__ float sigm(float v) { return 1.f / (1.f + __expf(-v)); }
__device__ __forceinline__ float tanh_fast(float v) { return 2.f / (1.f + __expf(-2.f * v)) - 1.f; }

__global__ __launch_bounds__(NTHR, 2) void gru_all(KArgs a) {
  const int bid = blockIdx.x, tid = threadIdx.x;
  const int gtid = bid * NTHR + tid, gsz = NBLK * NTHR;
  cg::grid_group grid = cg::this_grid();

  // ---------- setup: transpose weights for coalesced K-loops; copy h0 ----------
  for (int i = gtid; i < NIN * G3N; i += gsz) { int gc = i % G3N, k = i / G3N; a.WT_ih[i] = a.W_ih[gc * NIN + k]; }
  for (int i = gtid; i < HSN * G3N; i += gsz) { int gc = i % G3N, k = i / G3N; a.WT_hh[i] = a.W_hh[gc * HSN + k]; }
  for (int i = gtid; i < T1N * OUTN; i += gsz) { int o = i % OUTN, t = i / OUTN; a.WregT[i] = a.W_reg[o * T1N + t]; }
  for (int i = gtid; i < T1N * HSN; i += gsz) a.hb0[i] = a.h0[i];
  if (gtid < OUTN) {  // row-sums of W_reg for the folded b_hr contribution
    float s = 0.f; const float* wr = a.W_reg + gtid * T1N;
    for (int t = 0; t < T1N; ++t) s += wr[t];
    a.Sreg[gtid] = s;
  }
  grid.sync();

  // Padded LDS tiles: stride 132/260 spreads the per-k column reads over banks
  __shared__ float lx[32 * 132];   // x tile: 32 rows x 128
  __shared__ float lh[32 * 260];   // h tile: 32 rows x 256 (full rows)

  for (int s = 0; s < EPN + 2; ++s) {
    float* hprev = (s & 1) ? a.hb1 : a.hb0;   // h_new(s-1) == input h for step s
    float* hnext = (s & 1) ? a.hb0 : a.hb1;

    if (bid < A_BLOCKS) {
      if (s < EPN) {
        const int t0 = (bid >> 3) * 32, c0 = (bid & 7) * 32;
        // stage x (32x128, contiguous) and h rows (32x256, contiguous)
        const float4* xs = (const float4*)(a.x + ((size_t)s * T1N + t0) * NIN);
        #pragma unroll
        for (int j = 0; j < 4; ++j) {
          int e = tid + j * NTHR;                       // 1024 float4
          float4 v = xs[e];
          *(float4*)&lx[(e >> 5) * 132 + (e & 31) * 4] = v;
        }
        const float4* hs = (const float4*)(hprev + (size_t)t0 * HSN);
        #pragma unroll
        for (int j = 0; j < 8; ++j) {
          int e = tid + j * NTHR;                       // 2048 float4
          float4 v = hs[e];
          *(float4*)&lh[(e >> 6) * 260 + (e & 63) * 4] = v;
        }
        __syncthreads();

        const int tt = tid & 31;
        const int c  = c0 + (tid >> 5) * 4;             // 4 consecutive hidden cols
        F4 accr{0,0,0,0}, accz{0,0,0,0}, accn{0,0,0,0}, acchn{0,0,0,0};
        const int base = c >> 2;

        const float4* Wi = (const float4*)a.WT_ih;      // [k][768] transposed
        #pragma unroll 4
        for (int k = 0; k < NIN; ++k) {
          float xv = lx[tt * 132 + k];
          const float4* p = Wi + (size_t)k * (G3N / 4) + base;
          float4 wr = p[0], wz = p[64], wn = p[128];
          fma4(accr, xv, wr); fma4(accz, xv, wz); fma4(accn, xv, wn);
        }
        const float4* Wh = (const float4*)a.WT_hh;
        #pragma unroll 4
        for (int k = 0; k < HSN; ++k) {
          float hv = lh[tt * 260 + k];
          const float4* p = Wh + (size_t)k * (G3N / 4) + base;
          float4 wr = p[0], wz = p[64], wn = p[128];
          fma4(accr, hv, wr); fma4(accz, hv, wz); fma4(acchn, hv, wn);
        }
        // gates
        float4 bir  = *(const float4*)(a.b_ih + c);
        float4 bhr  = *(const float4*)(a.b_hh + c);
        float4 biz  = *(const float4*)(a.b_ih + HSN + c);
        float4 bhz  = *(const float4*)(a.b_hh + HSN + c);
        float4 bin_ = *(const float4*)(a.b_ih + 2 * HSN + c);
        float4 bhn  = *(const float4*)(a.b_hh + 2 * HSN + c);
        float rr[4]  = {accr.x + bir.x + bhr.x,  accr.y + bir.y + bhr.y,
                        accr.z + bir.z + bhr.z,  accr.w + bir.w + bhr.w};
        float zz[4]  = {accz.x + biz.x + bhz.x,  accz.y + biz.y + bhz.y,
                        accz.z + biz.z + bhz.z,  accz.w + biz.w + bhz.w};
        float ni[4]  = {accn.x + bin_.x, accn.y + bin_.y, accn.z + bin_.z, accn.w + bin_.w};
        float nh[4]  = {acchn.x + bhn.x, acchn.y + bhn.y, acchn.z + bhn.z, acchn.w + bhn.w};
        float4 hv4;
        float* ho = (float*)&hv4;
        #pragma unroll
        for (int j = 0; j < 4; ++j) {
          float r  = sigm(rr[j]);
          float z  = sigm(zz[j]);
          float nv = tanh_fast(ni[j] + r * nh[j]);
          float hp = lh[tt * 260 + c + j];
          ho[j] = (1.f - z) * nv + z * hp;
        }
        *(float4*)&hnext[((size_t)(t0 + tt)) * HSN + c] = hv4;
      }
    } else if (bid < A_BLOCKS + B_BLOCKS) {
      // P(s-1)[hh][o] = sum_t h_new(s-1)[t,hh] * W_reg[o,t]   (h_new(s-1) == hprev)
      if (s >= 1 && s <= EPN) {
        const int b = bid - A_BLOCKS;
        const int hh0 = (b >> 1) * 32, o0 = (b & 1) * 32;
        const int hc = tid & 31;
        const int oo = o0 + (tid >> 5) * 4;
        F4 acc{0,0,0,0};
        const float* hr = hprev + hh0 + hc;
        const float4* Wt = (const float4*)a.WregT + (oo >> 2);  // [t][64] transposed
        #pragma unroll 4
        for (int t = 0; t < T1N; ++t) {
          float hv = hr[(size_t)t * HSN];
          float4 w = Wt[t * (OUTN / 4)];
          fma4(acc, hv, w);
        }
        float* ptw = (s & 1) ? a.PT1 : a.PT0;
        *(float4*)&ptw[(hh0 + hc) * OUTN + oo] = make_float4(acc.x, acc.y, acc.z, acc.w);
      }
    } else {
      // final(s-2)[n][o] = sum_hh W_hr[n,hh] * P(s-2)[hh][o] + b_hr[n]*Sreg[o] + b_reg[o]
      if (s >= 2) {
        const int ep = s - 2;
        const int b = bid - A_BLOCKS - B_BLOCKS;
        const int o = tid & 63, nn2 = tid >> 6;
        const int n = b * 4 + nn2;
        const float* pt = (s & 1) ? a.PT0 : a.PT1;   // written by B at slot s-1
        const float* wh = a.W_hr + (size_t)n * HSN;
        float acc = 0.f;
        #pragma unroll 4
        for (int hh = 0; hh < HSN; ++hh) acc += pt[hh * OUTN + o] * wh[hh];
        a.out[((size_t)ep * NIN + n) * OUTN + o] = acc + a.b_hr[n] * a.Sreg[o] + a.b_reg[o];
      }
    }
    grid.sync();
  }
}

extern "C" void kernel_launch(void* const* d_in, const int* in_sizes, int n_in,
                              void* d_out, int out_size, void* d_ws, size_t ws_size,
                              hipStream_t stream) {
  KArgs a;
  a.x     = (const float*)d_in[0];
  a.h0    = (const float*)d_in[1];
  a.W_ih  = (const float*)d_in[2];
  a.W_hh  = (const float*)d_in[3];
  a.b_ih  = (const float*)d_in[4];
  a.b_hh  = (const float*)d_in[5];
  a.W_hr  = (const float*)d_in[6];
  a.b_hr  = (const float*)d_in[7];
  a.W_reg = (const float*)d_in[8];
  a.b_reg = (const float*)d_in[9];
  a.out   = (float*)d_out;

  float* ws = (float*)d_ws;                 // ~3.5 MB total
  a.WT_ih = ws; ws += NIN * G3N;
  a.WT_hh = ws; ws += HSN * G3N;
  a.WregT = ws; ws += T1N * OUTN;
  a.Sreg  = ws; ws += 64;
  a.hb0   = ws; ws += T1N * HSN;
  a.hb1   = ws; ws += T1N * HSN;
  a.PT0   = ws; ws += HSN * OUTN;
  a.PT1   = ws; ws += HSN * OUTN;

  void* kargs[] = { &a };
  hipLaunchCooperativeKernel((const void*)gru_all, dim3(NBLK), dim3(NTHR), kargs, 0, stream);
}

// Round 2
// 19344.492 us; speedup vs baseline: 2.7358x; 2.7358x over previous
//
#include <hip/hip_runtime.h>
#include <hip/hip_bf16.h>
#include <hip/hip_cooperative_groups.h>

namespace cg = cooperative_groups;

#define EPN  512
#define T1N  1024
#define NIN  128
#define HSN  256
#define OUTN 64

#define NBLK 256
#define NTHR 256

typedef __attribute__((ext_vector_type(8))) short bf16x8;
typedef __attribute__((ext_vector_type(4))) float f32x4;

struct KArgs {
  const float *x, *h0, *W_ih, *W_hh, *b_ih, *b_hh, *W_hr, *b_hr, *W_reg, *b_reg;
  float *out;
  float *WregT, *Sreg, *hb0, *hb1, *Ppart, *Pbuf;
};

__device__ __forceinline__ float sigm(float v) { return 1.f / (1.f + __expf(-v)); }
__device__ __forceinline__ float tanh_fast(float v) { return 2.f / (1.f + __expf(-2.f * v)) - 1.f; }
__device__ __forceinline__ ushort f2bf(float f) {
  return __builtin_bit_cast(ushort, __float2bfloat16(f));
}
__device__ __forceinline__ bf16x8 cvt8(float4 a, float4 b) {
  bf16x8 r;
  r[0]=(short)f2bf(a.x); r[1]=(short)f2bf(a.y); r[2]=(short)f2bf(a.z); r[3]=(short)f2bf(a.w);
  r[4]=(short)f2bf(b.x); r[5]=(short)f2bf(b.y); r[6]=(short)f2bf(b.z); r[7]=(short)f2bf(b.w);
  return r;
}

__global__ __launch_bounds__(NTHR, 1) void gru_mfma(KArgs a) {
  const int bid = blockIdx.x, tid = threadIdx.x;
  const int gtid = bid * NTHR + tid, gsz = NBLK * NTHR;
  cg::grid_group grid = cg::this_grid();

  const int tgrp = bid >> 4, cgrp = bid & 15;   // 16 t-groups x 16 c-groups
  const int t0 = tgrp * 64, c0 = cgrp * 16;

  __shared__ __align__(16) ushort WxL[48 * 128];   // 12 KB, swizzled bf16
  __shared__ __align__(16) ushort WhL[48 * 256];   // 24 KB, swizzled bf16
  __shared__ float red[NTHR];

  // ---------------- setup ----------------
  for (int i = gtid; i < T1N * OUTN; i += gsz) { int o = i & 63, t = i >> 6; a.WregT[i] = a.W_reg[o * T1N + t]; }
  for (int i = gtid; i < T1N * HSN; i += gsz) a.hb0[i] = a.h0[i];
  if (gtid < OUTN) {
    float s = 0.f; const float* wr = a.W_reg + gtid * T1N;
    for (int t = 0; t < T1N; ++t) s += wr[t];
    a.Sreg[gtid] = s;
  }
  // weight slices -> LDS (bf16, XOR-swizzled rows)
  for (int i = tid; i < 48 * 32; i += NTHR) {
    int gl = i >> 5, k4 = (i & 31) << 2;
    int gg = (gl >> 4) * HSN + c0 + (gl & 15);
    float4 wv = *(const float4*)&a.W_ih[gg * NIN + k4];
    int bi = ((gl << 7) + k4) ^ ((gl & 7) << 3);
    WxL[bi+0]=f2bf(wv.x); WxL[bi+1]=f2bf(wv.y); WxL[bi+2]=f2bf(wv.z); WxL[bi+3]=f2bf(wv.w);
  }
  for (int i = tid; i < 48 * 64; i += NTHR) {
    int gl = i >> 6, k4 = (i & 63) << 2;
    int gg = (gl >> 4) * HSN + c0 + (gl & 15);
    float4 wv = *(const float4*)&a.W_hh[gg * HSN + k4];
    int bi = ((gl << 8) + k4) ^ ((gl & 7) << 3);
    WhL[bi+0]=f2bf(wv.x); WhL[bi+1]=f2bf(wv.y); WhL[bi+2]=f2bf(wv.z); WhL[bi+3]=f2bf(wv.w);
  }

  // per-lane constants
  const int lane = tid & 63, wv_ = tid >> 6;      // 4 waves
  const int cl = lane & 15, kg = lane >> 4;
  const int tb = t0 + wv_ * 16;
  const int c  = c0 + cl;
  const float bR  = a.b_ih[c] + a.b_hh[c];
  const float bZ  = a.b_ih[HSN + c] + a.b_hh[HSN + c];
  const float bIN = a.b_ih[2*HSN + c];
  const float bHN = a.b_hh[2*HSN + c];
  const int sw = (cl & 7) << 3;

  grid.sync();

  // prefetch x frags for s = 0
  float4 xr0[4], xr1[4];
  {
    const float* xrow = a.x + (size_t)(tb + cl) * NIN + kg * 8;
    #pragma unroll
    for (int ks = 0; ks < 4; ++ks) { const float4* p = (const float4*)(xrow + ks * 32); xr0[ks] = p[0]; xr1[ks] = p[1]; }
  }

  for (int s = 0; s < EPN + 3; ++s) {
    const float* hprev = (s & 1) ? a.hb1 : a.hb0;
    float*       hnext = (s & 1) ? a.hb0 : a.hb1;

    // ---------------- A: h_new(s) ----------------
    if (s < EPN) {
      const float* hrow = hprev + (size_t)(tb + cl) * HSN + kg * 8;
      float4 hr0[8], hr1[8];
      #pragma unroll
      for (int ks = 0; ks < 8; ++ks) { const float4* p = (const float4*)(hrow + ks * 32); hr0[ks] = p[0]; hr1[ks] = p[1]; }
      float hp[4];
      #pragma unroll
      for (int r = 0; r < 4; ++r) hp[r] = hprev[(size_t)(tb + kg * 4 + r) * HSN + c];

      f32x4 accR = {0,0,0,0}, accZ = {0,0,0,0}, accNX = {0,0,0,0}, accNH = {0,0,0,0};
      #pragma unroll
      for (int ks = 0; ks < 4; ++ks) {                 // x part, K=128
        bf16x8 af = cvt8(xr0[ks], xr1[ks]);
        int k0 = ks * 32 + kg * 8;
        bf16x8 br = *(const bf16x8*)&WxL[(((     cl) << 7) + k0) ^ sw];
        bf16x8 bz = *(const bf16x8*)&WxL[(((16 + cl) << 7) + k0) ^ sw];
        bf16x8 bn = *(const bf16x8*)&WxL[(((32 + cl) << 7) + k0) ^ sw];
        accR  = __builtin_amdgcn_mfma_f32_16x16x32_bf16(af, br, accR,  0, 0, 0);
        accZ  = __builtin_amdgcn_mfma_f32_16x16x32_bf16(af, bz, accZ,  0, 0, 0);
        accNX = __builtin_amdgcn_mfma_f32_16x16x32_bf16(af, bn, accNX, 0, 0, 0);
      }
      #pragma unroll
      for (int ks = 0; ks < 8; ++ks) {                 // h part, K=256
        bf16x8 af = cvt8(hr0[ks], hr1[ks]);
        int k0 = ks * 32 + kg * 8;
        bf16x8 br = *(const bf16x8*)&WhL[(((     cl) << 8) + k0) ^ sw];
        bf16x8 bz = *(const bf16x8*)&WhL[(((16 + cl) << 8) + k0) ^ sw];
        bf16x8 bn = *(const bf16x8*)&WhL[(((32 + cl) << 8) + k0) ^ sw];
        accR  = __builtin_amdgcn_mfma_f32_16x16x32_bf16(af, br, accR,  0, 0, 0);
        accZ  = __builtin_amdgcn_mfma_f32_16x16x32_bf16(af, bz, accZ,  0, 0, 0);
        accNH = __builtin_amdgcn_mfma_f32_16x16x32_bf16(af, bn, accNH, 0, 0, 0);
      }
      #pragma unroll
      for (int r = 0; r < 4; ++r) {
        float rr = sigm(accR[r] + bR);
        float zz = sigm(accZ[r] + bZ);
        float nn = tanh_fast(accNX[r] + bIN + rr * (accNH[r] + bHN));
        hnext[(size_t)(tb + kg * 4 + r) * HSN + c] = (1.f - zz) * nn + zz * hp[r];
      }
    }

    // ---------------- B: P-partials for h(s-1), over this block's 64 t-rows ----------------
    if (s >= 1 && s <= EPN) {
      const int ci = tid & 15, og = tid >> 4;
      float ax = 0.f, ay = 0.f, az2 = 0.f, aw = 0.f;
      const float* hcol = hprev + (size_t)t0 * HSN + c0 + ci;
      const float4* wt = (const float4*)a.WregT;
      #pragma unroll 4
      for (int t = 0; t < 64; ++t) {
        float hv = hcol[(size_t)t * HSN];
        float4 w4 = wt[(t0 + t) * 16 + og];
        ax += hv * w4.x; ay += hv * w4.y; az2 += hv * w4.z; aw += hv * w4.w;
      }
      float* pp = a.Ppart + ((size_t)(s & 1) * 16 + tgrp) * 16384 + (c0 + ci) * 64 + og * 4;
      pp[0] = ax; pp[1] = ay; pp[2] = az2; pp[3] = aw;
    }

    // ---------------- P-reduce for h(s-2) ----------------
    if (s >= 2 && s <= EPN + 1 && tid < 64) {
      int idx = bid * 64 + tid;
      const float* pp = a.Ppart + (size_t)((s - 1) & 1) * 16 * 16384;
      float acc = 0.f;
      #pragma unroll
      for (int t = 0; t < 16; ++t) acc += pp[t * 16384 + idx];
      a.Pbuf[(size_t)(s & 1) * 16384 + idx] = acc;
    }

    // ---------------- C: final(s-3) ----------------
    if (s >= 3) {
      const int ep = s - 3;
      const int n0 = bid >> 1, oh = (bid & 1) * 32;
      const int oo = tid & 31, part = tid >> 5;
      const float* P = a.Pbuf + (size_t)((s - 1) & 1) * 16384;
      const float* wh = a.W_hr + n0 * HSN;
      float acc = 0.f;
      #pragma unroll 8
      for (int j = 0; j < 32; ++j) { int hh = part * 32 + j; acc += wh[hh] * P[hh * 64 + oh + oo]; }
      red[tid] = acc;
      __syncthreads();
      if (tid < 32) {
        float tsum = 0.f;
        #pragma unroll
        for (int p = 0; p < 8; ++p) tsum += red[p * 32 + tid];
        a.out[((size_t)ep * NIN + n0) * OUTN + oh + tid] =
            tsum + a.b_hr[n0] * a.Sreg[oh + tid] + a.b_reg[oh + tid];
      }
    }

    // prefetch x frags for s+1 (independent of everything above)
    if (s + 1 < EPN) {
      const float* xrow = a.x + ((size_t)(s + 1) * T1N + tb + cl) * NIN + kg * 8;
      #pragma unroll
      for (int ks = 0; ks < 4; ++ks) { const float4* p = (const float4*)(xrow + ks * 32); xr0[ks] = p[0]; xr1[ks] = p[1]; }
    }

    grid.sync();
  }
}

extern "C" void kernel_launch(void* const* d_in, const int* in_sizes, int n_in,
                              void* d_out, int out_size, void* d_ws, size_t ws_size,
                              hipStream_t stream) {
  KArgs a;
  a.x     = (const float*)d_in[0];
  a.h0    = (const float*)d_in[1];
  a.W_ih  = (const float*)d_in[2];
  a.W_hh  = (const float*)d_in[3];
  a.b_ih  = (const float*)d_in[4];
  a.b_hh  = (const float*)d_in[5];
  a.W_hr  = (const float*)d_in[6];
  a.b_hr  = (const float*)d_in[7];
  a.W_reg = (const float*)d_in[8];
  a.b_reg = (const float*)d_in[9];
  a.out   = (float*)d_out;

  float* ws = (float*)d_ws;
  a.WregT = ws; ws += T1N * OUTN;        // 65536
  a.Sreg  = ws; ws += 64;
  a.hb0   = ws; ws += T1N * HSN;         // 262144
  a.hb1   = ws; ws += T1N * HSN;         // 262144
  a.Ppart = ws; ws += 2 * 16 * 16384;    // 524288
  a.Pbuf  = ws; ws += 2 * 16384;         // 32768

  void* kargs[] = { &a };
  hipLaunchCooperativeKernel((const void*)gru_mfma, dim3(NBLK), dim3(NTHR), kargs, 0, stream);
}

// Round 5
// 6492.046 us; speedup vs baseline: 8.1518x; 2.9797x over previous
//
#include <hip/hip_runtime.h>
#include <hip/hip_bf16.h>

#define EPN  512
#define T1N  1024
#define NIN  128
#define HSN  256
#define OUTN 64
#define NBLK 256
#define NTHR 256

typedef __attribute__((ext_vector_type(8))) short bf16x8;
typedef __attribute__((ext_vector_type(4))) short bf16x4;
typedef __attribute__((ext_vector_type(4))) float f32x4;

struct KArgs {
  const float *x, *h0, *W_ih, *W_hh, *b_ih, *b_hh, *W_hr, *b_hr, *W_reg, *b_reg;
  float *out;
  ushort *hb;            // [2][1024][256] bf16 recurrent state (L3-coherent)
  float *Ppart;          // [2][16][64][256]
  float *Pbuf;           // [2][64][256]
  float *Sreg;           // [64]
  unsigned int *flags;   // [256] per-block progress (monotonic)
};

__device__ __forceinline__ float sigm(float v) { return 1.f / (1.f + __expf(-v)); }
__device__ __forceinline__ float tanh_fast(float v) { return 2.f / (1.f + __expf(-2.f * v)) - 1.f; }
__device__ __forceinline__ short f2bf(float f) {
  return (short)__builtin_bit_cast(ushort, __float2bfloat16(f));
}
__device__ __forceinline__ bf16x8 cvt8(f32x4 a, f32x4 b) {
  bf16x8 r;
  r[0]=f2bf(a[0]); r[1]=f2bf(a[1]); r[2]=f2bf(a[2]); r[3]=f2bf(a[3]);
  r[4]=f2bf(b[0]); r[5]=f2bf(b[1]); r[6]=f2bf(b[2]); r[7]=f2bf(b[3]);
  return r;
}

// ---- coherent-at-L3 (L1/L2-bypassing) ops for cross-block data ----
__device__ __forceinline__ bf16x8 ld16h_sc(const ushort* p) {
  bf16x8 v; asm volatile("global_load_dwordx4 %0, %1, off sc0 sc1" : "=v"(v) : "v"(p)); return v;
}
__device__ __forceinline__ f32x4 ld16f_sc(const float* p) {
  f32x4 v; asm volatile("global_load_dwordx4 %0, %1, off sc0 sc1" : "=v"(v) : "v"(p)); return v;
}
__device__ __forceinline__ float ld4f_sc(const float* p) {
  float v; asm volatile("global_load_dword %0, %1, off sc0 sc1" : "=v"(v) : "v"(p)); return v;
}
__device__ __forceinline__ void st16f_sc(float* p, f32x4 v) {
  asm volatile("global_store_dwordx4 %0, %1, off sc0 sc1" :: "v"(p), "v"(v) : "memory");
}
__device__ __forceinline__ void st8h_sc(ushort* p, bf16x4 v) {
  asm volatile("global_store_dwordx2 %0, %1, off sc0 sc1" :: "v"(p), "v"(v) : "memory");
}
__device__ __forceinline__ void st4f_sc(float* p, float v) {
  asm volatile("global_store_dword %0, %1, off sc0 sc1" :: "v"(p), "v"(v) : "memory");
}
// plain (cacheable) load for read-only x
__device__ __forceinline__ f32x4 ld16f(const float* p) {
  f32x4 v; asm volatile("global_load_dwordx4 %0, %1, off" : "=v"(v) : "v"(p)); return v;
}
#define WAITV0 do { asm volatile("s_waitcnt vmcnt(0)" ::: "memory"); \
                    __builtin_amdgcn_sched_barrier(0); } while (0)

// Distributed-flag grid barrier with bounded spin (safety: wrong-answer, never hang).
__device__ __forceinline__ void fbar(unsigned int* flags, int bid, int tid, unsigned int target) {
  asm volatile("s_waitcnt vmcnt(0)" ::: "memory");
  __syncthreads();                          // every wave has drained its loads/stores
  if (tid == 0)
    __hip_atomic_store(&flags[bid], target, __ATOMIC_RELEASE, __HIP_MEMORY_SCOPE_SYSTEM);
  if (tid < 64) {
    int spins = 0;
    bool ok = false;
    while (!ok) {
      unsigned int m = 0xFFFFFFFFu;
      #pragma unroll
      for (int j = 0; j < 4; ++j) {
        unsigned int v = __hip_atomic_load(&flags[tid + j * 64], __ATOMIC_RELAXED,
                                           __HIP_MEMORY_SCOPE_SYSTEM);
        m = (v < m) ? v : m;
      }
      ok = __all(m >= target);
      if (!ok) {
        if (++spins > (1 << 20)) break;     // safety valve
        __builtin_amdgcn_s_sleep(1);
      }
    }
  }
  __syncthreads();
}

#define MFMA(A,B,C) __builtin_amdgcn_mfma_f32_16x16x32_bf16(A, B, C, 0, 0, 0)

// ---------------- setup kernel (ordinary launch #1) ----------------
__global__ void gru_setup(KArgs a) {
  const int gtid = blockIdx.x * blockDim.x + threadIdx.x;
  const int gsz = gridDim.x * blockDim.x;
  if (gtid < NBLK) a.flags[gtid] = 0;
  for (int i = gtid; i < T1N * HSN; i += gsz)
    a.hb[i] = __builtin_bit_cast(ushort, __float2bfloat16(a.h0[i]));  // parity 0
  if (gtid < OUTN) {
    float ssum = 0.f; const float* wr = a.W_reg + (size_t)gtid * T1N;
    for (int t = 0; t < T1N; ++t) ssum += wr[t];
    a.Sreg[gtid] = ssum;
  }
}

// ---------------- main persistent kernel (ordinary launch #2) ----------------
__global__ __launch_bounds__(NTHR, 1) void gru5(KArgs a) {
  const int bid = blockIdx.x, tid = threadIdx.x;

  const int tgrp = bid >> 4, cgrp = bid & 15;
  const int t0 = tgrp * 64, c0 = cgrp * 16;

  __shared__ __align__(16) short WxL[48 * 128];  // 12 KB, swizzled
  __shared__ __align__(16) short WhL[48 * 256];  // 24 KB, swizzled
  __shared__ __align__(16) short WtL[64 * 80];   // 10 KB (W_reg tile, stride 80)
  __shared__ __align__(16) short hT [16 * 80];   // 2.5 KB (h_new^T, stride 80)
  __shared__ float cpart[256];

  // ---- weights -> LDS (bf16) ----
  for (int i = tid; i < 48 * 32; i += NTHR) {
    int gl = i >> 5, k4 = (i & 31) << 2;
    int gg = (gl >> 4) * HSN + c0 + (gl & 15);
    f32x4 wv = *(const f32x4*)&a.W_ih[(size_t)gg * NIN + k4];
    int bi = ((gl << 7) + k4) ^ ((gl & 7) << 3);
    WxL[bi+0]=f2bf(wv[0]); WxL[bi+1]=f2bf(wv[1]); WxL[bi+2]=f2bf(wv[2]); WxL[bi+3]=f2bf(wv[3]);
  }
  for (int i = tid; i < 48 * 64; i += NTHR) {
    int gl = i >> 6, k4 = (i & 63) << 2;
    int gg = (gl >> 4) * HSN + c0 + (gl & 15);
    f32x4 wv = *(const f32x4*)&a.W_hh[(size_t)gg * HSN + k4];
    int bi = ((gl << 8) + k4) ^ ((gl & 7) << 3);
    WhL[bi+0]=f2bf(wv[0]); WhL[bi+1]=f2bf(wv[1]); WhL[bi+2]=f2bf(wv[2]); WhL[bi+3]=f2bf(wv[3]);
  }
  {
    int o = tid >> 2, seg = tid & 3;
    const float* wr = a.W_reg + (size_t)o * T1N + t0 + seg * 16;
    bf16x8 p0, p1;
    #pragma unroll
    for (int j = 0; j < 8; ++j) p0[j] = f2bf(wr[j]);
    #pragma unroll
    for (int j = 0; j < 8; ++j) p1[j] = f2bf(wr[8 + j]);
    *(bf16x8*)&WtL[o * 80 + seg * 16]     = p0;
    *(bf16x8*)&WtL[o * 80 + seg * 16 + 8] = p1;
  }
  __syncthreads();

  // per-lane constants
  const int lane = tid & 63, wv_ = tid >> 6;
  const int cl = lane & 15, kg = lane >> 4;
  const int tb = t0 + wv_ * 16;
  const int c  = c0 + cl;
  const float bR  = a.b_ih[c] + a.b_hh[c];
  const float bZ  = a.b_ih[HSN + c] + a.b_hh[HSN + c];
  const float bIN = a.b_ih[2*HSN + c];
  const float bHN = a.b_hh[2*HSN + c];
  const int sw = (cl & 7) << 3;

  // C-phase constants
  const int n0 = bid >> 1, oh = (bid & 1) * 32;
  const int oo = tid & 31, part = tid >> 5;
  f32x4 whr[8];
  #pragma unroll
  for (int j = 0; j < 8; ++j) whr[j] = *(const f32x4*)&a.W_hr[(size_t)n0 * HSN + part * 32 + j * 4];
  const float cb = a.b_hr[n0];
  const float sregv = a.Sreg[oh + oo];     // written by setup kernel (prior launch)
  const float bregv = a.b_reg[oh + oo];

  // fp32 recurrent state for this block's own (t,c) tile lives in registers
  float hp[4];
  #pragma unroll
  for (int r = 0; r < 4; ++r) hp[r] = a.h0[(size_t)(tb + kg * 4 + r) * HSN + c];

  // gi(0) = x(0) @ W_ih^T -> registers
  f32x4 giR = {0,0,0,0}, giZ = {0,0,0,0}, giN = {0,0,0,0};
  {
    const float* xrow = a.x + (size_t)(tb + cl) * NIN + kg * 8;
    #pragma unroll
    for (int ks = 0; ks < 4; ++ks) {
      f32x4 x0 = *(const f32x4*)(xrow + ks * 32);
      f32x4 x1 = *(const f32x4*)(xrow + ks * 32 + 4);
      bf16x8 af = cvt8(x0, x1);
      int k0 = ks * 32 + kg * 8;
      bf16x8 br = *(const bf16x8*)&WxL[(((     cl) << 7) + k0) ^ sw];
      bf16x8 bz = *(const bf16x8*)&WxL[(((16 + cl) << 7) + k0) ^ sw];
      bf16x8 bn = *(const bf16x8*)&WxL[(((32 + cl) << 7) + k0) ^ sw];
      giR = MFMA(af, br, giR); giZ = MFMA(af, bz, giZ); giN = MFMA(af, bn, giN);
    }
  }

  // ---------------- main pipeline: 514 slots ----------------
  for (int s = 0; s < EPN + 2; ++s) {
    const ushort* hb_r = a.hb + (size_t)(s & 1) * (T1N * HSN);
    ushort*       hb_w = a.hb + (size_t)((s + 1) & 1) * (T1N * HSN);

    // -- batch-issue ALL global loads for this slot --
    bf16x8 hfr[8];
    if (s < EPN) {
      const ushort* hrow = hb_r + (size_t)(tb + cl) * HSN + kg * 8;
      #pragma unroll
      for (int ks = 0; ks < 8; ++ks) hfr[ks] = ld16h_sc(hrow + ks * 32);
    }
    float rv[16];
    if (tid < 64 && s >= 1 && s <= EPN) {
      const float* pp = a.Ppart + (size_t)((s - 1) & 1) * (16 * 16384) + bid * 64 + tid;
      #pragma unroll
      for (int j = 0; j < 16; ++j) rv[j] = ld4f_sc(pp + (size_t)j * 16384);
    }
    f32x4 cv[8];
    if (s >= 2) {
      const float* pb = a.Pbuf + (size_t)((s - 1) & 1) * 16384 + (size_t)(oh + oo) * 256 + part * 32;
      #pragma unroll
      for (int j = 0; j < 8; ++j) cv[j] = ld16f_sc(pb + j * 4);
    }
    f32x4 xa[4], xb[4];
    const bool hasX = (s + 1 < EPN);
    if (hasX) {
      const float* xrow = a.x + ((size_t)(s + 1) * T1N + tb + cl) * NIN + kg * 8;
      #pragma unroll
      for (int ks = 0; ks < 4; ++ks) {
        xa[ks] = ld16f(xrow + ks * 32);
        xb[ks] = ld16f(xrow + ks * 32 + 4);
      }
    }
    WAITV0;   // one safe wait: every load above has arrived, for every wave

    // -- h-GEMM: gates for step s (K=256, 24 MFMA) --
    f32x4 accR = {0,0,0,0}, accZ = {0,0,0,0}, accN = {0,0,0,0};
    if (s < EPN) {
      #pragma unroll
      for (int ks = 0; ks < 8; ++ks) {
        int k0 = ks * 32 + kg * 8;
        bf16x8 br = *(const bf16x8*)&WhL[(((     cl) << 8) + k0) ^ sw];
        bf16x8 bz = *(const bf16x8*)&WhL[(((16 + cl) << 8) + k0) ^ sw];
        bf16x8 bn = *(const bf16x8*)&WhL[(((32 + cl) << 8) + k0) ^ sw];
        accR = MFMA(hfr[ks], br, accR);
        accZ = MFMA(hfr[ks], bz, accZ);
        accN = MFMA(hfr[ks], bn, accN);
      }
    }

    // -- P-reduce for h(s-1): sum 16 tgrp partials --
    if (tid < 64 && s >= 1 && s <= EPN) {
      float sum = 0.f;
      #pragma unroll
      for (int j = 0; j < 16; ++j) sum += rv[j];
      st4f_sc(a.Pbuf + (size_t)(s & 1) * 16384 + bid * 64 + tid, sum);
    }

    // -- C partial: final(s-2) dot over this thread's 32 hh --
    if (s >= 2) {
      float cacc = 0.f;
      #pragma unroll
      for (int j = 0; j < 8; ++j)
        cacc += whr[j][0]*cv[j][0] + whr[j][1]*cv[j][1] + whr[j][2]*cv[j][2] + whr[j][3]*cv[j][3];
      cpart[part * 32 + oo] = cacc;
    }

    // -- gi-GEMM for step s+1 (x part, K=128, 12 MFMA) --
    f32x4 giR2 = {0,0,0,0}, giZ2 = {0,0,0,0}, giN2 = {0,0,0,0};
    if (hasX) {
      #pragma unroll
      for (int ks = 0; ks < 4; ++ks) {
        bf16x8 af = cvt8(xa[ks], xb[ks]);
        int k0 = ks * 32 + kg * 8;
        bf16x8 br = *(const bf16x8*)&WxL[(((     cl) << 7) + k0) ^ sw];
        bf16x8 bz = *(const bf16x8*)&WxL[(((16 + cl) << 7) + k0) ^ sw];
        bf16x8 bn = *(const bf16x8*)&WxL[(((32 + cl) << 7) + k0) ^ sw];
        giR2 = MFMA(af, br, giR2); giZ2 = MFMA(af, bz, giZ2); giN2 = MFMA(af, bn, giN2);
      }
    }

    // -- epilogue: gates -> h_new (fp32 state in regs, bf16 to LDS) --
    if (s < EPN) {
      bf16x4 hpk;
      #pragma unroll
      for (int r = 0; r < 4; ++r) {
        float rr = sigm(accR[r] + giR[r] + bR);
        float zz = sigm(accZ[r] + giZ[r] + bZ);
        float nn = tanh_fast(giN[r] + bIN + rr * (accN[r] + bHN));
        float hn = (1.f - zz) * nn + zz * hp[r];
        hp[r] = hn;
        hpk[r] = f2bf(hn);
      }
      *(bf16x4*)&hT[cl * 80 + wv_ * 16 + kg * 4] = hpk;   // h^T tile [16c][64t]
    }
    giR = giR2; giZ = giZ2; giN = giN2;

    __syncthreads();

    if (s < EPN) {
      // -- B: P-partial via MFMA on this block's own h_new (M=hh16, N=o64, K=t64) --
      f32x4 pacc = {0,0,0,0};
      #pragma unroll
      for (int ks = 0; ks < 2; ++ks) {
        bf16x8 pa = *(const bf16x8*)&hT[cl * 80 + ks * 32 + kg * 8];
        bf16x8 pb = *(const bf16x8*)&WtL[(wv_ * 16 + cl) * 80 + ks * 32 + kg * 8];
        pacc = MFMA(pa, pb, pacc);
      }
      st16f_sc(a.Ppart + ((size_t)(s & 1) * 16 + tgrp) * 16384 + (size_t)(wv_ * 16 + cl) * 256 + c0 + kg * 4, pacc);

      // -- h_new -> global (bf16, coalesced 8B per thread) --
      int th = tid >> 2, c4 = (tid & 3) * 4;
      bf16x4 hpk2;
      #pragma unroll
      for (int j = 0; j < 4; ++j) hpk2[j] = hT[(c4 + j) * 80 + th];
      st8h_sc(hb_w + (size_t)(t0 + th) * HSN + c0 + c4, hpk2);
    }

    // -- final output for epoch s-2 --
    if (s >= 2 && tid < 32) {
      float v = cb * sregv + bregv;
      #pragma unroll
      for (int p = 0; p < 8; ++p) v += cpart[p * 32 + tid];
      st4f_sc(a.out + ((size_t)(s - 2) * NIN + n0) * OUTN + oh + tid, v);
    }

    fbar(a.flags, bid, tid, (unsigned int)(s + 1));
  }
}

extern "C" void kernel_launch(void* const* d_in, const int* in_sizes, int n_in,
                              void* d_out, int out_size, void* d_ws, size_t ws_size,
                              hipStream_t stream) {
  KArgs a;
  a.x     = (const float*)d_in[0];
  a.h0    = (const float*)d_in[1];
  a.W_ih  = (const float*)d_in[2];
  a.W_hh  = (const float*)d_in[3];
  a.b_ih  = (const float*)d_in[4];
  a.b_hh  = (const float*)d_in[5];
  a.W_hr  = (const float*)d_in[6];
  a.b_hr  = (const float*)d_in[7];
  a.W_reg = (const float*)d_in[8];
  a.b_reg = (const float*)d_in[9];
  a.out   = (float*)d_out;

  char* w = (char*)d_ws;                       // ~3.3 MB total
  a.hb    = (ushort*)w;       w += (size_t)2 * T1N * HSN * 2;
  a.Ppart = (float*)w;        w += (size_t)2 * 16 * 16384 * 4;
  a.Pbuf  = (float*)w;        w += (size_t)2 * 16384 * 4;
  a.Sreg  = (float*)w;        w += 256;
  a.flags = (unsigned int*)w; w += NBLK * 4;

  hipLaunchKernelGGL(gru_setup, dim3(64), dim3(NTHR), 0, stream, a);
  hipLaunchKernelGGL(gru5, dim3(NBLK), dim3(NTHR), 0, stream, a);
}

// Round 6
// 3830.482 us; speedup vs baseline: 13.8161x; 1.6948x over previous
//
#include <hip/hip_runtime.h>
#include <hip/hip_bf16.h>

#define EPN  512
#define T1N  1024
#define NIN  128
#define HSN  256
#define OUTN 64
#define NBLK 256
#define NTHR 256

typedef __attribute__((ext_vector_type(8))) short bf16x8;
typedef __attribute__((ext_vector_type(4))) short bf16x4;
typedef __attribute__((ext_vector_type(4))) float f32x4;
typedef __attribute__((ext_vector_type(4))) unsigned int u32x4;

struct KArgs {
  const float *x, *h0, *W_ih, *W_hh, *b_ih, *b_hh, *W_hr, *b_hr, *W_reg, *b_reg;
  float *out;
  ushort *hb;            // [2][1024][256] bf16 recurrent state (L3-coherent)
  float *Ppart;          // [2][16][64][256]
  float *Pbuf;           // [2][64][256]
  float *Sreg;           // [64]
  unsigned int *hflags;  // [16][16]  h-ready per (tgrp,cgrp), monotonic
  unsigned int *pflags;  // [256]     slot-complete per block, monotonic
};

__device__ __forceinline__ float sigm(float v) { return 1.f / (1.f + __expf(-v)); }
__device__ __forceinline__ float tanh_fast(float v) { return 2.f / (1.f + __expf(-2.f * v)) - 1.f; }
__device__ __forceinline__ short f2bf(float f) {
  return (short)__builtin_bit_cast(ushort, __float2bfloat16(f));
}
__device__ __forceinline__ bf16x8 cvt8(f32x4 a, f32x4 b) {
  bf16x8 r;
  r[0]=f2bf(a[0]); r[1]=f2bf(a[1]); r[2]=f2bf(a[2]); r[3]=f2bf(a[3]);
  r[4]=f2bf(b[0]); r[5]=f2bf(b[1]); r[6]=f2bf(b[2]); r[7]=f2bf(b[3]);
  return r;
}

// ---- coherent-at-L3 (L1/L2-bypassing) ops for cross-block data ----
__device__ __forceinline__ bf16x8 ld16h_sc(const ushort* p) {
  bf16x8 v; asm volatile("global_load_dwordx4 %0, %1, off sc0 sc1" : "=v"(v) : "v"(p)); return v;
}
__device__ __forceinline__ f32x4 ld16f_sc(const float* p) {
  f32x4 v; asm volatile("global_load_dwordx4 %0, %1, off sc0 sc1" : "=v"(v) : "v"(p)); return v;
}
__device__ __forceinline__ u32x4 ld16u_sc(const unsigned int* p) {
  u32x4 v; asm volatile("global_load_dwordx4 %0, %1, off sc0 sc1" : "=v"(v) : "v"(p)); return v;
}
__device__ __forceinline__ float ld4f_sc(const float* p) {
  float v; asm volatile("global_load_dword %0, %1, off sc0 sc1" : "=v"(v) : "v"(p)); return v;
}
__device__ __forceinline__ void st16f_sc(float* p, f32x4 v) {
  asm volatile("global_store_dwordx4 %0, %1, off sc0 sc1" :: "v"(p), "v"(v) : "memory");
}
__device__ __forceinline__ void st8h_sc(ushort* p, bf16x4 v) {
  asm volatile("global_store_dwordx2 %0, %1, off sc0 sc1" :: "v"(p), "v"(v) : "memory");
}
__device__ __forceinline__ void st4f_sc(float* p, float v) {
  asm volatile("global_store_dword %0, %1, off sc0 sc1" :: "v"(p), "v"(v) : "memory");
}
__device__ __forceinline__ void st4u_sc(unsigned int* p, unsigned int v) {
  asm volatile("global_store_dword %0, %1, off sc0 sc1" :: "v"(p), "v"(v) : "memory");
}
// plain (cacheable) load for read-only x
__device__ __forceinline__ f32x4 ld16f(const float* p) {
  f32x4 v; asm volatile("global_load_dwordx4 %0, %1, off" : "=v"(v) : "v"(p)); return v;
}
#define WAITV0 do { asm volatile("s_waitcnt vmcnt(0)" ::: "memory"); \
                    __builtin_amdgcn_sched_barrier(0); } while (0)

__device__ __forceinline__ unsigned int min4(u32x4 v) {
  unsigned int m = v[0];
  m = v[1] < m ? v[1] : m; m = v[2] < m ? v[2] : m; m = v[3] < m ? v[3] : m;
  return m;
}
// wave0 polls nquad coalesced dwordx4 flag quads until all >= target; bounded spin.
__device__ __forceinline__ void waitflags(const unsigned int* f, int nquad,
                                          unsigned int target, int tid) {
  if (tid < 64) {
    int spins = 0;
    for (;;) {
      unsigned int m = 0xFFFFFFFFu;
      if (tid < nquad) m = min4(ld16u_sc(f + tid * 4));
      asm volatile("s_waitcnt vmcnt(0)" ::: "memory");
      if (__all((int)(m >= target))) break;
      if (++spins > (1 << 17)) break;          // safety valve: wrong answer, never hang
      __builtin_amdgcn_s_sleep(2);
    }
  }
  __syncthreads();
}

#define MFMA(A,B,C) __builtin_amdgcn_mfma_f32_16x16x32_bf16(A, B, C, 0, 0, 0)

// ---------------- setup kernel (ordinary launch #1) ----------------
__global__ void gru_setup(KArgs a) {
  const int gtid = blockIdx.x * blockDim.x + threadIdx.x;
  const int gsz = gridDim.x * blockDim.x;
  if (gtid < 512) { if (gtid < 256) a.hflags[gtid] = 0; else a.pflags[gtid - 256] = 0; }
  for (int i = gtid; i < T1N * HSN; i += gsz)
    a.hb[i] = __builtin_bit_cast(ushort, __float2bfloat16(a.h0[i]));  // parity 0
  if (gtid < OUTN) {
    float ssum = 0.f; const float* wr = a.W_reg + (size_t)gtid * T1N;
    for (int t = 0; t < T1N; ++t) ssum += wr[t];
    a.Sreg[gtid] = ssum;
  }
}

// ---------------- main persistent kernel (ordinary launch #2) ----------------
__global__ __launch_bounds__(NTHR, 1) void gru6(KArgs a) {
  const int bid = blockIdx.x, tid = threadIdx.x;

  // XCD clustering: bid % 8 = XCD; tgrp = bid&15 keeps all 16 sharers of a
  // t-row-range (same x rows, same h rows) on one XCD for L2 reuse of x.
  const int tgrp = bid & 15, cgrp = bid >> 4;
  const int t0 = tgrp * 64, c0 = cgrp * 16;

  __shared__ __align__(16) short WtL[64 * 80];   // 10 KB: W_reg tile (bf16, stride 80)
  __shared__ __align__(16) short hT [16 * 80];   // 2.5 KB: h_new^T tile
  __shared__ float cpart[256];

  // ---- W_reg tile -> LDS (bf16) ----
  {
    int o = tid >> 2, seg = tid & 3;
    const float* wr = a.W_reg + (size_t)o * T1N + t0 + seg * 16;
    bf16x8 p0, p1;
    #pragma unroll
    for (int j = 0; j < 8; ++j) p0[j] = f2bf(wr[j]);
    #pragma unroll
    for (int j = 0; j < 8; ++j) p1[j] = f2bf(wr[8 + j]);
    *(bf16x8*)&WtL[o * 80 + seg * 16]     = p0;
    *(bf16x8*)&WtL[o * 80 + seg * 16 + 8] = p1;
  }
  __syncthreads();

  // per-lane constants
  const int lane = tid & 63, wv_ = tid >> 6;     // 4 waves
  const int cl = lane & 15, kg = lane >> 4;
  const int tb = t0 + wv_ * 16;
  const int c  = c0 + cl;
  const float bR  = a.b_ih[c] + a.b_hh[c];
  const float bZ  = a.b_ih[HSN + c] + a.b_hh[HSN + c];
  const float bIN = a.b_ih[2*HSN + c];
  const float bHN = a.b_hh[2*HSN + c];

  // ---- recurrent weights -> REGISTERS (constant all 512 steps; 1 wave/SIMD
  // via launch_bounds(256,1) leaves VGPR headroom to 512) ----
  bf16x8 whR[8], whZ[8], whN[8];                 // W_hh fragments, K=256
  #pragma unroll
  for (int ks = 0; ks < 8; ++ks) {
    const float* pr = a.W_hh + (size_t)(0*HSN + c) * HSN + ks * 32 + kg * 8;
    const float* pz = a.W_hh + (size_t)(1*HSN + c) * HSN + ks * 32 + kg * 8;
    const float* pn = a.W_hh + (size_t)(2*HSN + c) * HSN + ks * 32 + kg * 8;
    whR[ks] = cvt8(*(const f32x4*)pr, *(const f32x4*)(pr + 4));
    whZ[ks] = cvt8(*(const f32x4*)pz, *(const f32x4*)(pz + 4));
    whN[ks] = cvt8(*(const f32x4*)pn, *(const f32x4*)(pn + 4));
  }
  bf16x8 wxR[4], wxZ[4], wxN[4];                 // W_ih fragments, K=128
  #pragma unroll
  for (int ks = 0; ks < 4; ++ks) {
    const float* pr = a.W_ih + (size_t)(0*HSN + c) * NIN + ks * 32 + kg * 8;
    const float* pz = a.W_ih + (size_t)(1*HSN + c) * NIN + ks * 32 + kg * 8;
    const float* pn = a.W_ih + (size_t)(2*HSN + c) * NIN + ks * 32 + kg * 8;
    wxR[ks] = cvt8(*(const f32x4*)pr, *(const f32x4*)(pr + 4));
    wxZ[ks] = cvt8(*(const f32x4*)pz, *(const f32x4*)(pz + 4));
    wxN[ks] = cvt8(*(const f32x4*)pn, *(const f32x4*)(pn + 4));
  }

  // C-phase constants
  const int n0 = bid >> 1, oh = (bid & 1) * 32;
  const int oo = tid & 31, part = tid >> 5;
  f32x4 whr[8];
  #pragma unroll
  for (int j = 0; j < 8; ++j) whr[j] = *(const f32x4*)&a.W_hr[(size_t)n0 * HSN + part * 32 + j * 4];
  const float cb = a.b_hr[n0];
  const float sregv = a.Sreg[oh + oo];           // from setup launch
  const float bregv = a.b_reg[oh + oo];

  // fp32 recurrent state for this block's own (t,c) tile lives in registers
  float hp[4];
  #pragma unroll
  for (int r = 0; r < 4; ++r) hp[r] = a.h0[(size_t)(tb + kg * 4 + r) * HSN + c];

  // gi(0) = x(0) @ W_ih^T -> registers
  f32x4 giR = {0,0,0,0}, giZ = {0,0,0,0}, giN = {0,0,0,0};
  {
    const float* xrow = a.x + (size_t)(tb + cl) * NIN + kg * 8;
    #pragma unroll
    for (int ks = 0; ks < 4; ++ks) {
      f32x4 x0 = *(const f32x4*)(xrow + ks * 32);
      f32x4 x1 = *(const f32x4*)(xrow + ks * 32 + 4);
      bf16x8 af = cvt8(x0, x1);
      giR = MFMA(af, wxR[ks], giR); giZ = MFMA(af, wxZ[ks], giZ); giN = MFMA(af, wxN[ks], giN);
    }
  }

  // ---------------- main pipeline: 514 slots ----------------
  for (int s = 0; s < EPN + 2; ++s) {
    const ushort* hb_r = a.hb + (size_t)(s & 1) * (T1N * HSN);
    ushort*       hb_w = a.hb + (size_t)((s + 1) & 1) * (T1N * HSN);

    // S0: wait only on the 16 tgrp-mates' h flags (one dwordx4 quad x 4 lanes)
    if (s >= 1 && s < EPN) waitflags(a.hflags + tgrp * 16, 4, (unsigned)s, tid);

    // S1: issue h + x loads, one safe wait
    bf16x8 hfr[8];
    if (s < EPN) {
      const ushort* hrow = hb_r + (size_t)(tb + cl) * HSN + kg * 8;
      #pragma unroll
      for (int ks = 0; ks < 8; ++ks) hfr[ks] = ld16h_sc(hrow + ks * 32);
    }
    f32x4 xa[4], xb[4];
    const bool hasX = (s + 1 < EPN);
    if (hasX) {
      const float* xrow = a.x + ((size_t)(s + 1) * T1N + tb + cl) * NIN + kg * 8;
      #pragma unroll
      for (int ks = 0; ks < 4; ++ks) {
        xa[ks] = ld16f(xrow + ks * 32);
        xb[ks] = ld16f(xrow + ks * 32 + 4);
      }
    }
    WAITV0;

    // S2: h-GEMM (24 MFMA, all operands in registers) + epilogue
    if (s < EPN) {
      f32x4 accR = {0,0,0,0}, accZ = {0,0,0,0}, accN = {0,0,0,0};
      #pragma unroll
      for (int ks = 0; ks < 8; ++ks) {
        accR = MFMA(hfr[ks], whR[ks], accR);
        accZ = MFMA(hfr[ks], whZ[ks], accZ);
        accN = MFMA(hfr[ks], whN[ks], accN);
      }
      bf16x4 hpk;
      #pragma unroll
      for (int r = 0; r < 4; ++r) {
        float rr = sigm(accR[r] + giR[r] + bR);
        float zz = sigm(accZ[r] + giZ[r] + bZ);
        float nn = tanh_fast(giN[r] + bIN + rr * (accN[r] + bHN));
        float hn = (1.f - zz) * nn + zz * hp[r];
        hp[r] = hn;
        hpk[r] = f2bf(hn);
      }
      *(bf16x4*)&hT[cl * 80 + wv_ * 16 + kg * 4] = hpk;   // h^T tile [16c][64t]
    }
    __syncthreads();                                       // hT visible

    // S3: h -> global (coalesced 8B/thread), drain, EARLY h flag
    if (s < EPN) {
      int th = tid >> 2, c4 = (tid & 3) * 4;
      bf16x4 hpk2;
      #pragma unroll
      for (int j = 0; j < 4; ++j) hpk2[j] = hT[(c4 + j) * 80 + th];
      st8h_sc(hb_w + (size_t)(t0 + th) * HSN + c0 + c4, hpk2);
    }
    WAITV0;
    __syncthreads();                                       // all waves drained
    if (s < EPN && tid == 0) st4u_sc(a.hflags + tgrp * 16 + cgrp, (unsigned)(s + 1));

    // S4: gi-GEMM for s+1 (register weights)
    f32x4 giR2 = {0,0,0,0}, giZ2 = {0,0,0,0}, giN2 = {0,0,0,0};
    if (hasX) {
      #pragma unroll
      for (int ks = 0; ks < 4; ++ks) {
        bf16x8 af = cvt8(xa[ks], xb[ks]);
        giR2 = MFMA(af, wxR[ks], giR2); giZ2 = MFMA(af, wxZ[ks], giZ2); giN2 = MFMA(af, wxN[ks], giN2);
      }
    }
    giR = giR2; giZ = giZ2; giN = giN2;

    // S5: wait slot-(s-1) completion of ALL blocks (propagation overlapped
    // with S1-S4); gates Ppart/Pbuf reads AND makes 2-deep reuse safe.
    if (s >= 1) waitflags(a.pflags, 64, (unsigned)s, tid);

    // S6: P pipeline
    float rv[16];
    if (tid < 64 && s >= 1 && s <= EPN) {
      const float* pp = a.Ppart + (size_t)((s - 1) & 1) * (16 * 16384) + bid * 64 + tid;
      #pragma unroll
      for (int j = 0; j < 16; ++j) rv[j] = ld4f_sc(pp + (size_t)j * 16384);
    }
    f32x4 cv[8];
    if (s >= 2) {
      const float* pb = a.Pbuf + (size_t)((s - 1) & 1) * 16384 + (size_t)(oh + oo) * 256 + part * 32;
      #pragma unroll
      for (int j = 0; j < 8; ++j) cv[j] = ld16f_sc(pb + j * 4);
    }
    WAITV0;
    if (s < EPN) {                                   // B: P-partial via MFMA on own h_new
      f32x4 pacc = {0,0,0,0};
      #pragma unroll
      for (int ks = 0; ks < 2; ++ks) {
        bf16x8 pa = *(const bf16x8*)&hT[cl * 80 + ks * 32 + kg * 8];
        bf16x8 pb = *(const bf16x8*)&WtL[(wv_ * 16 + cl) * 80 + ks * 32 + kg * 8];
        pacc = MFMA(pa, pb, pacc);
      }
      st16f_sc(a.Ppart + ((size_t)(s & 1) * 16 + tgrp) * 16384 + (size_t)(wv_ * 16 + cl) * 256 + c0 + kg * 4, pacc);
    }
    if (tid < 64 && s >= 1 && s <= EPN) {            // P-reduce
      float sum = 0.f;
      #pragma unroll
      for (int j = 0; j < 16; ++j) sum += rv[j];
      st4f_sc(a.Pbuf + (size_t)(s & 1) * 16384 + bid * 64 + tid, sum);
    }
    if (s >= 2) {                                    // C partial
      float cacc = 0.f;
      #pragma unroll
      for (int j = 0; j < 8; ++j)
        cacc += whr[j][0]*cv[j][0] + whr[j][1]*cv[j][1] + whr[j][2]*cv[j][2] + whr[j][3]*cv[j][3];
      cpart[part * 32 + oo] = cacc;
    }
    __syncthreads();
    if (s >= 2 && tid < 32) {                        // final out(s-2)
      float v = cb * sregv + bregv;
      #pragma unroll
      for (int p = 0; p < 8; ++p) v += cpart[p * 32 + tid];
      st4f_sc(a.out + ((size_t)(s - 2) * NIN + n0) * OUTN + oh + tid, v);
    }

    // S7: drain everything, end-of-slot flag
    WAITV0;
    __syncthreads();
    if (tid == 0) st4u_sc(a.pflags + bid, (unsigned)(s + 1));
  }
}

extern "C" void kernel_launch(void* const* d_in, const int* in_sizes, int n_in,
                              void* d_out, int out_size, void* d_ws, size_t ws_size,
                              hipStream_t stream) {
  KArgs a;
  a.x     = (const float*)d_in[0];
  a.h0    = (const float*)d_in[1];
  a.W_ih  = (const float*)d_in[2];
  a.W_hh  = (const float*)d_in[3];
  a.b_ih  = (const float*)d_in[4];
  a.b_hh  = (const float*)d_in[5];
  a.W_hr  = (const float*)d_in[6];
  a.b_hr  = (const float*)d_in[7];
  a.W_reg = (const float*)d_in[8];
  a.b_reg = (const float*)d_in[9];
  a.out   = (float*)d_out;

  char* w = (char*)d_ws;                       // ~3.2 MB total
  a.hb     = (ushort*)w;       w += (size_t)2 * T1N * HSN * 2;
  a.Ppart  = (float*)w;        w += (size_t)2 * 16 * 16384 * 4;
  a.Pbuf   = (float*)w;        w += (size_t)2 * 16384 * 4;
  a.Sreg   = (float*)w;        w += 256;
  a.hflags = (unsigned int*)w; w += 256 * 4;
  a.pflags = (unsigned int*)w; w += 256 * 4;

  hipLaunchKernelGGL(gru_setup, dim3(64), dim3(NTHR), 0, stream, a);
  hipLaunchKernelGGL(gru6, dim3(NBLK), dim3(NTHR), 0, stream, a);
}